// Round 10
// baseline (413.959 us; speedup 1.0000x reference)
//
#include <hip/hip_runtime.h>
#include <hip/hip_bf16.h>

using f32x4 = __attribute__((ext_vector_type(4))) float;
using bf16x8 = __attribute__((ext_vector_type(8))) short;

#define DEVI __device__ __forceinline__

DEVI short f2bf(float f) { __hip_bfloat16 h = __float2bfloat16(f); return *reinterpret_cast<short*>(&h); }
DEVI unsigned int pk2(float a, float b) {
    float2 t; t.x = a; t.y = b;
    __hip_bfloat162 h = __float22bfloat162_rn(t);
    return *reinterpret_cast<unsigned int*>(&h);
}
DEVI float bf2f(unsigned short s) { unsigned int u = ((unsigned int)s) << 16; return __uint_as_float(u); }

// gfx950 cross-lane-group swaps (both operands modified)
DEVI void pl32swap(unsigned& a, unsigned& b) { asm("v_permlane32_swap_b32 %0, %1" : "+v"(a), "+v"(b)); }
DEVI void pl16swap(unsigned& a, unsigned& b) { asm("v_permlane16_swap_b32 %0, %1" : "+v"(a), "+v"(b)); }

// async global->LDS, 16B per lane
#define GLOAD_LDS16(gp, lp) \
    __builtin_amdgcn_global_load_lds((const __attribute__((address_space(1))) void*)(gp), \
                                     (__attribute__((address_space(3))) void*)(lp), 16, 0, 0)

constexpr int NB = 8192;   // windows
constexpr int NT = 49;     // tokens per window
constexpr int CD = 128;    // channels
constexpr float SCALE = 0.17677669529663687f; // 32^-0.5
constexpr float LOG2E = 1.4426950408889634f;

// ---- ws layout (bytes) ----
constexpr size_t WS_QKVWT  = 0;        // 384*128 bf16 swizzled
constexpr size_t WS_PROJWT = 98304;    // 128*128 bf16 plain-transposed [n][k]
constexpr size_t WS_BIAS   = 131072;   // 4*2401 bf16 transposed [h][k][q] x LOG2E
constexpr size_t WS_QKV    = 150528;
constexpr size_t SQKV      = (size_t)NB * 4 * NT * 32;

DEVI void div49(unsigned grow, unsigned& bI, unsigned& tI) {
    bI = (unsigned)(((unsigned long long)grow * 2804876602ull) >> 37);
    tI = grow - bI * 49u;
}

// swizzled index into a [64][128] bf16 tile
DEVI int swz128(int row, int col) { return row * 128 + (col ^ ((row & 7) << 3)); }

// ============================================================================
// prep: qkv weights transposed+pre-swizzled (for gload_lds+XOR path);
// proj weights PLAIN transposed [n][k] (read direct from global in fused B);
// bias gathered transposed [h][k][q], x LOG2E.
// ============================================================================
__global__ __launch_bounds__(256) void prep_kernel(
    const float* __restrict__ qkv_w, const float* __restrict__ proj_w,
    const float* __restrict__ rbt, const int* __restrict__ rel_index,
    short* __restrict__ qkvwS, short* __restrict__ projwT, unsigned short* __restrict__ biasBf)
{
    int i = blockIdx.x * 256 + threadIdx.x;
    if (i < 384 * 128) {
        int n = i >> 7, j = i & 127;
        int c = n >> 7, r = n & 127;
        qkvwS[c * 16384 + r * 128 + (j ^ ((r & 7) << 3))] = f2bf(qkv_w[j * 384 + n]);
    }
    if (i < 128 * 128) {
        int n = i >> 7, j = i & 127;
        projwT[n * 128 + j] = f2bf(proj_w[j * 128 + n]);
    }
    if (i < 4 * NT * NT) {
        int h = i / (NT * NT); int t = i % (NT * NT);
        int k = t / NT, q = t - k * NT;
        biasBf[i] = (unsigned short)f2bf(rbt[rel_index[q * NT + k] * 4 + h] * LOG2E);
    }
}

// ============================================================================
// Kernel A: QKV GEMM (unchanged from R9). q pre-scaled by SCALE*LOG2E.
// ============================================================================
__global__ __launch_bounds__(256, 2) void qkv_gemm_kernel(
    const float* __restrict__ x, const float* __restrict__ qkv_b,
    const short* __restrict__ qkvwS, short* __restrict__ qkv)
{
    __shared__ short ldsB[16384];
    const int tid = threadIdx.x;
    const int w = tid >> 6, lane = tid & 63, lr = lane & 15, lg = lane >> 4;
    const unsigned m0 = blockIdx.x * 128 + w * 32;

    bf16x8 af[2][4];
#pragma unroll
    for (int mf = 0; mf < 2; ++mf) {
        const float* xrow = x + (size_t)(m0 + mf * 16 + lr) * CD;
#pragma unroll
        for (int kt = 0; kt < 4; ++kt) {
            const float4* p = reinterpret_cast<const float4*>(xrow + kt * 32 + lg * 8);
            float4 v0 = p[0], v1 = p[1];
            union { unsigned int u[4]; bf16x8 v; } cv;
            cv.u[0] = pk2(v0.x, v0.y); cv.u[1] = pk2(v0.z, v0.w);
            cv.u[2] = pk2(v1.x, v1.y); cv.u[3] = pk2(v1.z, v1.w);
            af[mf][kt] = cv.v;
        }
    }

    unsigned rowoff[2][4];
#pragma unroll
    for (int mf = 0; mf < 2; ++mf)
#pragma unroll
        for (int r = 0; r < 4; ++r) {
            unsigned bI, tI;
            div49(m0 + mf * 16 + 4 * lg + r, bI, tI);
            rowoff[mf][r] = bI * 6272u + tI * 32u;
        }

    const char* srcB = (const char*)qkvwS;
    char* ldsBc = (char*)ldsB;

#pragma unroll
    for (int c = 0; c < 3; ++c) {
#pragma unroll
        for (int i = 0; i < 8; ++i)
            GLOAD_LDS16(srcB + c * 32768 + w * 8192 + i * 1024 + lane * 16,
                        ldsBc + w * 8192 + i * 1024);
        __syncthreads();

        f32x4 acc[2][8];
#pragma unroll
        for (int mf = 0; mf < 2; ++mf)
#pragma unroll
            for (int n = 0; n < 8; ++n) acc[mf][n] = f32x4{0.f, 0.f, 0.f, 0.f};

#pragma unroll
        for (int ntl = 0; ntl < 8; ++ntl) {
            const int rrow = ntl * 16 + lr;
            const char* rbase = ldsBc + rrow * 256;
            const int sw = (lr & 7) << 4;
#pragma unroll
            for (int kt = 0; kt < 4; ++kt) {
                bf16x8 bb = *reinterpret_cast<const bf16x8*>(rbase + ((kt * 64 + lg * 16) ^ sw));
                acc[0][ntl] = __builtin_amdgcn_mfma_f32_16x16x32_bf16(af[0][kt], bb, acc[0][ntl], 0, 0, 0);
                acc[1][ntl] = __builtin_amdgcn_mfma_f32_16x16x32_bf16(af[1][kt], bb, acc[1][ntl], 0, 0, 0);
            }
        }

        const float scl = (c == 0) ? SCALE * LOG2E : 1.0f;
        short* dplane = qkv + (size_t)c * SQKV;
#pragma unroll
        for (int ntl = 0; ntl < 8; ++ntl) {
            const int h = ntl >> 1;
            const int d = (ntl & 1) * 16 + lr;
            const float bias = qkv_b[c * 128 + ntl * 16 + lr];
#pragma unroll
            for (int mf = 0; mf < 2; ++mf)
#pragma unroll
                for (int r = 0; r < 4; ++r)
                    dplane[rowoff[mf][r] + h * 1568 + d] = f2bf((acc[mf][ntl][r] + bias) * scl);
        }
        __syncthreads();
    }
}

// ============================================================================
// Kernel B: FUSED attention + proj. block = window (512 thr, 8 waves).
// attn: wave = (head, query-half), swapped-QK^T in-register softmax (R9).
// o -> LDS swz128 tile; barrier; proj: wave = (row-tile, col-half), A from
// LDS, B direct from L2-hot projwT, fp32 out stores.
// LDS: mT[50*65] 13000 + vS 16384 + oS 16384 = 45768 B -> 3 blocks/CU.
// ============================================================================
__global__ __launch_bounds__(512, 6) void attn_proj_kernel(
    const short* __restrict__ qkv, const float* __restrict__ mask,
    const unsigned short* __restrict__ biasT, const short* __restrict__ projwT,
    const float* __restrict__ proj_b, float* __restrict__ out)
{
    __shared__ float mT[50 * 65];          // transposed mask x LOG2E; stride 65
    __shared__ short vS[4][2048];          // V slot-permuted cols, XOR-swizzled
    __shared__ short oS[64 * 128];         // o tile, swz128

    const int b = blockIdx.x;
    const int tid = threadIdx.x;
    const int w = tid >> 6, lane = tid & 63, lr = lane & 15, lg = lane >> 4;
    const int h = w >> 1, half = w & 1;

    const size_t slice = (size_t)(b * 4 + h) * (NT * 32);
    const short* qg = qkv + slice;
    const short* kg = qkv + SQKV + slice;
    const short* vg = qkv + 2 * SQKV + slice;
    short* vSl = vS[h];

    // ---- zero mT (LDS-only, cheap) ----
    for (int i = tid; i < 50 * 65; i += 512) mT[i] = 0.f;

    // ---- Q/K fragments (global, issued early) ----
    const int mt0 = 2 * half;
    bf16x8 qa[2], kb[4];
#pragma unroll
    for (int i = 0; i < 2; ++i)
        qa[i] = *reinterpret_cast<const bf16x8*>(qg + (16 * (mt0 + i) + lr) * 32 + lg * 8);
#pragma unroll
    for (int t4 = 0; t4 < 4; ++t4)
        kb[t4] = *reinterpret_cast<const bf16x8*>(kg + (16 * t4 + lr) * 32 + lg * 8);

    // ---- mask prefetch to regs (coalesced; hides HBM latency) ----
    const float* mb_ = mask + (size_t)b * (NT * NT);
    float mreg[5];
#pragma unroll
    for (int ii = 0; ii < 5; ++ii) {
        int i = tid + ii * 512;
        mreg[ii] = (i < NT * NT) ? mb_[i] * LOG2E : 0.f;
    }

    // ---- stage V: lanes map to consecutive tokens (bank-spread writes).
    // slot col for token tt=16a+bb: bb<8 -> 8a+bb, else 24+8a+bb.
    for (int ii = 0; ii < 4; ++ii) {
        int i = ii * 64 + lane;
        int tt = 32 * half + (i & 31);
        int d0 = (i >> 5) * 4;
        short4 v4 = {0, 0, 0, 0};
        if (tt < NT) v4 = *reinterpret_cast<const short4*>(vg + tt * 32 + d0);
        int a = tt >> 4, bb2 = tt & 15;
        int col = (bb2 < 8) ? (a * 8 + bb2) : (24 + a * 8 + bb2);
        vSl[(d0 + 0) * 64 + (col ^ (((d0 + 0) & 7) << 3))] = v4.x;
        vSl[(d0 + 1) * 64 + (col ^ (((d0 + 1) & 7) << 3))] = v4.y;
        vSl[(d0 + 2) * 64 + (col ^ (((d0 + 2) & 7) << 3))] = v4.z;
        vSl[(d0 + 3) * 64 + (col ^ (((d0 + 3) & 7) << 3))] = v4.w;
    }
    __syncthreads();   // #1: mT zeroed, vS staged

    // ---- scatter mask regs -> mT transposed (bank stride 1 per lane) ----
#pragma unroll
    for (int ii = 0; ii < 5; ++ii) {
        int i = tid + ii * 512;
        if (i < NT * NT) {
            unsigned q_, k_;
            div49((unsigned)i, q_, k_);
            mT[k_ * 65 + q_] = mreg[ii];
        }
    }
    __syncthreads();   // #2: mT ready

    // ---- hoisted V fragments ----
    bf16x8 vb[2][2];
    const int sw8 = (lr & 7) << 3;
#pragma unroll
    for (int nt = 0; nt < 2; ++nt)
#pragma unroll
        for (int blk = 0; blk < 2; ++blk)
            vb[nt][blk] = *reinterpret_cast<const bf16x8*>(
                &vSl[(16 * nt + lr) * 64 + ((blk * 32 + 8 * lg) ^ sw8)]);

    const unsigned short* biasTh = biasT + h * (NT * NT);

    f32x4 oacc[2][2];
#pragma unroll
    for (int mt2 = 0; mt2 < 2; ++mt2) { oacc[mt2][0] = f32x4{0,0,0,0}; oacc[mt2][1] = f32x4{0,0,0,0}; }

#pragma unroll
    for (int mt2 = 0; mt2 < 2; ++mt2) {
        const int mt = mt0 + mt2;
        const int qcol = 16 * mt + lr;

        float mb[4][4];
#pragma unroll
        for (int ct = 0; ct < 4; ++ct)
#pragma unroll
            for (int r = 0; r < 4; ++r) {
                int k = 16 * ct + 4 * lg + r;
                int kc = min(k, 49);
                mb[ct][r] = mT[kc * 65 + qcol] + bf2f(biasTh[kc * NT + qcol]);
            }

        f32x4 sacc[4];
#pragma unroll
        for (int ct = 0; ct < 4; ++ct) {
            f32x4 z = {0.f, 0.f, 0.f, 0.f};
            sacc[ct] = __builtin_amdgcn_mfma_f32_16x16x32_bf16(kb[ct], qa[mt2], z, 0, 0, 0);
        }

        float e[4][4];
        float psum = 0.f;
#pragma unroll
        for (int ct = 0; ct < 4; ++ct)
#pragma unroll
            for (int r = 0; r < 4; ++r) {
                float ee = exp2f(sacc[ct][r] + mb[ct][r]);
                if (ct == 3) ee = (r == 0 && lg == 0) ? ee : 0.f;
                e[ct][r] = ee;
                psum += ee;
            }
        psum += __shfl_xor(psum, 16);
        psum += __shfl_xor(psum, 32);
        const float inv = 1.0f / psum;

        unsigned A0 = pk2(e[0][0] * inv, e[0][1] * inv);
        unsigned A1 = pk2(e[1][0] * inv, e[1][1] * inv);
        unsigned A2 = pk2(e[2][0] * inv, e[2][1] * inv);
        unsigned A3 = pk2(e[3][0] * inv, e[3][1] * inv);
        unsigned B0 = pk2(e[0][2] * inv, e[0][3] * inv);
        unsigned B1 = pk2(e[1][2] * inv, e[1][3] * inv);
        unsigned B2 = pk2(e[2][2] * inv, e[2][3] * inv);
        unsigned B3 = pk2(e[3][2] * inv, e[3][3] * inv);
        pl32swap(A0, A2); pl32swap(A1, A3);
        pl16swap(A0, A1); pl16swap(A2, A3);
        pl32swap(B0, B2); pl32swap(B1, B3);
        pl16swap(B0, B1); pl16swap(B2, B3);
        union { unsigned u[4]; bf16x8 v; } p0, p1;
        p0.u[0] = A0; p0.u[1] = B0; p0.u[2] = A1; p0.u[3] = B1;
        p1.u[0] = A2; p1.u[1] = B2; p1.u[2] = A3; p1.u[3] = B3;

#pragma unroll
        for (int nt = 0; nt < 2; ++nt) {
            oacc[mt2][nt] = __builtin_amdgcn_mfma_f32_16x16x32_bf16(p0.v, vb[nt][0], oacc[mt2][nt], 0, 0, 0);
            oacc[mt2][nt] = __builtin_amdgcn_mfma_f32_16x16x32_bf16(p1.v, vb[nt][1], oacc[mt2][nt], 0, 0, 0);
        }
    }
    __syncthreads();   // #3: all mT/vS reads done

    // ---- write o tile to LDS (swz128) ----
#pragma unroll
    for (int mt2 = 0; mt2 < 2; ++mt2)
#pragma unroll
        for (int nt = 0; nt < 2; ++nt)
#pragma unroll
            for (int r = 0; r < 4; ++r) {
                int row = 16 * (mt0 + mt2) + 4 * lg + r;
                int col = 32 * h + 16 * nt + lr;
                oS[swz128(row, col)] = f2bf(oacc[mt2][nt][r]);
            }
    __syncthreads();   // #4: o ready

    // ---- proj: wave = (row-tile rt, col-half ch) ----
    {
        const int rt = w >> 1, ch = w & 1;

        bf16x8 af[4];
#pragma unroll
        for (int kt = 0; kt < 4; ++kt)
            af[kt] = *reinterpret_cast<const bf16x8*>(&oS[swz128(16 * rt + lr, kt * 32 + lg * 8)]);

        bf16x8 bbf[4][4];
#pragma unroll
        for (int ntl = 0; ntl < 4; ++ntl) {
            const short* brow = projwT + (ch * 64 + ntl * 16 + lr) * 128 + lg * 8;
#pragma unroll
            for (int kt = 0; kt < 4; ++kt)
                bbf[ntl][kt] = *reinterpret_cast<const bf16x8*>(brow + kt * 32);
        }

        f32x4 acc[4];
#pragma unroll
        for (int ntl = 0; ntl < 4; ++ntl) {
            acc[ntl] = f32x4{0.f, 0.f, 0.f, 0.f};
#pragma unroll
            for (int kt = 0; kt < 4; ++kt)
                acc[ntl] = __builtin_amdgcn_mfma_f32_16x16x32_bf16(af[kt], bbf[ntl][kt], acc[ntl], 0, 0, 0);
        }

#pragma unroll
        for (int ntl = 0; ntl < 4; ++ntl) {
            int col = ch * 64 + ntl * 16 + lr;
            float pb = proj_b[col];
#pragma unroll
            for (int r = 0; r < 4; ++r) {
                int row = 16 * rt + 4 * lg + r;
                if (row < NT)
                    out[((size_t)b * NT + row) * CD + col] = acc[ntl][r] + pb;
            }
        }
    }
}

extern "C" void kernel_launch(void* const* d_in, const int* in_sizes, int n_in,
                              void* d_out, int out_size, void* d_ws, size_t ws_size,
                              hipStream_t stream) {
    const float* x      = (const float*)d_in[0];
    const float* mask   = (const float*)d_in[1];
    const float* qkv_w  = (const float*)d_in[2];
    const float* qkv_b  = (const float*)d_in[3];
    const float* rbt    = (const float*)d_in[4];
    const float* proj_w = (const float*)d_in[5];
    const float* proj_b = (const float*)d_in[6];
    const int*   ridx   = (const int*)d_in[7];
    float* out = (float*)d_out;

    char* ws = (char*)d_ws;
    short* qkvwS  = (short*)(ws + WS_QKVWT);
    short* projwT = (short*)(ws + WS_PROJWT);
    unsigned short* biasBf = (unsigned short*)(ws + WS_BIAS);
    short* qkv = (short*)(ws + WS_QKV);

    prep_kernel<<<192, 256, 0, stream>>>(qkv_w, proj_w, rbt, ridx, qkvwS, projwT, biasBf);
    qkv_gemm_kernel<<<(NB * NT) / 128, 256, 0, stream>>>(x, qkv_b, qkvwS, qkv);
    attn_proj_kernel<<<NB, 512, 0, stream>>>(qkv, mask, biasBf, projwT, proj_b, out);
}

// Round 11
// 312.767 us; speedup vs baseline: 1.3235x; 1.3235x over previous
//
#include <hip/hip_runtime.h>
#include <hip/hip_bf16.h>

using f32x4 = __attribute__((ext_vector_type(4))) float;
using bf16x8 = __attribute__((ext_vector_type(8))) short;

#define DEVI __device__ __forceinline__

DEVI short f2bf(float f) { __hip_bfloat16 h = __float2bfloat16(f); return *reinterpret_cast<short*>(&h); }
DEVI unsigned int pk2(float a, float b) {
    float2 t; t.x = a; t.y = b;
    __hip_bfloat162 h = __float22bfloat162_rn(t);
    return *reinterpret_cast<unsigned int*>(&h);
}
DEVI float bf2f(unsigned short s) { unsigned int u = ((unsigned int)s) << 16; return __uint_as_float(u); }

// gfx950 cross-lane-group swaps (both operands modified)
DEVI void pl32swap(unsigned& a, unsigned& b) { asm("v_permlane32_swap_b32 %0, %1" : "+v"(a), "+v"(b)); }
DEVI void pl16swap(unsigned& a, unsigned& b) { asm("v_permlane16_swap_b32 %0, %1" : "+v"(a), "+v"(b)); }

// async global->LDS, 16B per lane
#define GLOAD_LDS16(gp, lp) \
    __builtin_amdgcn_global_load_lds((const __attribute__((address_space(1))) void*)(gp), \
                                     (__attribute__((address_space(3))) void*)(lp), 16, 0, 0)

constexpr int NB = 8192;   // windows
constexpr int NT = 49;     // tokens per window
constexpr int CD = 128;    // channels
constexpr float SCALE = 0.17677669529663687f; // 32^-0.5
constexpr float LOG2E = 1.4426950408889634f;

// ---- ws layout (bytes) ----
constexpr size_t WS_QKVWT  = 0;        // 384*128 bf16 swizzled
constexpr size_t WS_PROJWT = 98304;    // 128*128 bf16 plain-transposed [n][k]
constexpr size_t WS_BIAS   = 131072;   // 4*2401 bf16 transposed [h][k][q] x LOG2E
constexpr size_t WS_QKV    = 150528;
constexpr size_t SQKV      = (size_t)NB * 4 * NT * 32;

DEVI void div49(unsigned grow, unsigned& bI, unsigned& tI) {
    bI = (unsigned)(((unsigned long long)grow * 2804876602ull) >> 37);
    tI = grow - bI * 49u;
}

// swizzled index into a [64][128] bf16 tile
DEVI int swz128(int row, int col) { return row * 128 + (col ^ ((row & 7) << 3)); }

// ============================================================================
// prep (unchanged from R10)
// ============================================================================
__global__ __launch_bounds__(256) void prep_kernel(
    const float* __restrict__ qkv_w, const float* __restrict__ proj_w,
    const float* __restrict__ rbt, const int* __restrict__ rel_index,
    short* __restrict__ qkvwS, short* __restrict__ projwT, unsigned short* __restrict__ biasBf)
{
    int i = blockIdx.x * 256 + threadIdx.x;
    if (i < 384 * 128) {
        int n = i >> 7, j = i & 127;
        int c = n >> 7, r = n & 127;
        qkvwS[c * 16384 + r * 128 + (j ^ ((r & 7) << 3))] = f2bf(qkv_w[j * 384 + n]);
    }
    if (i < 128 * 128) {
        int n = i >> 7, j = i & 127;
        projwT[n * 128 + j] = f2bf(proj_w[j * 128 + n]);
    }
    if (i < 4 * NT * NT) {
        int h = i / (NT * NT); int t = i % (NT * NT);
        int k = t / NT, q = t - k * NT;
        biasBf[i] = (unsigned short)f2bf(rbt[rel_index[q * NT + k] * 4 + h] * LOG2E);
    }
}

// ============================================================================
// Kernel A: QKV GEMM (unchanged from R9/R10). q pre-scaled by SCALE*LOG2E.
// ============================================================================
__global__ __launch_bounds__(256, 2) void qkv_gemm_kernel(
    const float* __restrict__ x, const float* __restrict__ qkv_b,
    const short* __restrict__ qkvwS, short* __restrict__ qkv)
{
    __shared__ short ldsB[16384];
    const int tid = threadIdx.x;
    const int w = tid >> 6, lane = tid & 63, lr = lane & 15, lg = lane >> 4;
    const unsigned m0 = blockIdx.x * 128 + w * 32;

    bf16x8 af[2][4];
#pragma unroll
    for (int mf = 0; mf < 2; ++mf) {
        const float* xrow = x + (size_t)(m0 + mf * 16 + lr) * CD;
#pragma unroll
        for (int kt = 0; kt < 4; ++kt) {
            const float4* p = reinterpret_cast<const float4*>(xrow + kt * 32 + lg * 8);
            float4 v0 = p[0], v1 = p[1];
            union { unsigned int u[4]; bf16x8 v; } cv;
            cv.u[0] = pk2(v0.x, v0.y); cv.u[1] = pk2(v0.z, v0.w);
            cv.u[2] = pk2(v1.x, v1.y); cv.u[3] = pk2(v1.z, v1.w);
            af[mf][kt] = cv.v;
        }
    }

    unsigned rowoff[2][4];
#pragma unroll
    for (int mf = 0; mf < 2; ++mf)
#pragma unroll
        for (int r = 0; r < 4; ++r) {
            unsigned bI, tI;
            div49(m0 + mf * 16 + 4 * lg + r, bI, tI);
            rowoff[mf][r] = bI * 6272u + tI * 32u;
        }

    const char* srcB = (const char*)qkvwS;
    char* ldsBc = (char*)ldsB;

#pragma unroll
    for (int c = 0; c < 3; ++c) {
#pragma unroll
        for (int i = 0; i < 8; ++i)
            GLOAD_LDS16(srcB + c * 32768 + w * 8192 + i * 1024 + lane * 16,
                        ldsBc + w * 8192 + i * 1024);
        __syncthreads();

        f32x4 acc[2][8];
#pragma unroll
        for (int mf = 0; mf < 2; ++mf)
#pragma unroll
            for (int n = 0; n < 8; ++n) acc[mf][n] = f32x4{0.f, 0.f, 0.f, 0.f};

#pragma unroll
        for (int ntl = 0; ntl < 8; ++ntl) {
            const int rrow = ntl * 16 + lr;
            const char* rbase = ldsBc + rrow * 256;
            const int sw = (lr & 7) << 4;
#pragma unroll
            for (int kt = 0; kt < 4; ++kt) {
                bf16x8 bb = *reinterpret_cast<const bf16x8*>(rbase + ((kt * 64 + lg * 16) ^ sw));
                acc[0][ntl] = __builtin_amdgcn_mfma_f32_16x16x32_bf16(af[0][kt], bb, acc[0][ntl], 0, 0, 0);
                acc[1][ntl] = __builtin_amdgcn_mfma_f32_16x16x32_bf16(af[1][kt], bb, acc[1][ntl], 0, 0, 0);
            }
        }

        const float scl = (c == 0) ? SCALE * LOG2E : 1.0f;
        short* dplane = qkv + (size_t)c * SQKV;
#pragma unroll
        for (int ntl = 0; ntl < 8; ++ntl) {
            const int h = ntl >> 1;
            const int d = (ntl & 1) * 16 + lr;
            const float bias = qkv_b[c * 128 + ntl * 16 + lr];
#pragma unroll
            for (int mf = 0; mf < 2; ++mf)
#pragma unroll
                for (int r = 0; r < 4; ++r)
                    dplane[rowoff[mf][r] + h * 1568 + d] = f2bf((acc[mf][ntl][r] + bias) * scl);
        }
        __syncthreads();
    }
}

// ============================================================================
// Kernel B: FUSED attention + proj, v2.
//  - proj B prefetched at kernel top, deduped: wave w owns col-tile nt=w
//    (block B traffic = exactly 32KB)
//  - mask+bias for BOTH mt iterations hoisted before first QK^T
//  - barriers: 3 total (mT zero->scatter, scatter->read, oS write->proj read)
// LDS: mT[50*65] 13000 + vS 16384 + oS 16384 = 45768 B -> 3 blocks/CU.
// ============================================================================
__global__ __launch_bounds__(512, 4) void attn_proj_kernel(
    const short* __restrict__ qkv, const float* __restrict__ mask,
    const unsigned short* __restrict__ biasT, const short* __restrict__ projwT,
    const float* __restrict__ proj_b, float* __restrict__ out)
{
    __shared__ float mT[50 * 65];
    __shared__ short vS[4][2048];
    __shared__ short oS[64 * 128];

    const int b = blockIdx.x;
    const int tid = threadIdx.x;
    const int w = tid >> 6, lane = tid & 63, lr = lane & 15, lg = lane >> 4;
    const int h = w >> 1, half = w & 1;

    const size_t slice = (size_t)(b * 4 + h) * (NT * 32);
    const short* qg = qkv + slice;
    const short* kg = qkv + SQKV + slice;
    const short* vg = qkv + 2 * SQKV + slice;
    short* vSl = vS[h];

    // ---- proj B prefetch (independent; held through attn) ----
    bf16x8 bbf[4];
    {
        const short* brow = projwT + (w * 16 + lr) * 128 + lg * 8;
#pragma unroll
        for (int kt = 0; kt < 4; ++kt)
            bbf[kt] = *reinterpret_cast<const bf16x8*>(brow + kt * 32);
    }

    // ---- Q/K fragments (global, issued early) ----
    const int mt0 = 2 * half;
    bf16x8 qa[2], kb[4];
#pragma unroll
    for (int i = 0; i < 2; ++i)
        qa[i] = *reinterpret_cast<const bf16x8*>(qg + (16 * (mt0 + i) + lr) * 32 + lg * 8);
#pragma unroll
    for (int t4 = 0; t4 < 4; ++t4)
        kb[t4] = *reinterpret_cast<const bf16x8*>(kg + (16 * t4 + lr) * 32 + lg * 8);

    // ---- zero mT ----
    for (int i = tid; i < 50 * 65; i += 512) mT[i] = 0.f;

    // ---- mask prefetch to regs (coalesced) ----
    const float* mb_ = mask + (size_t)b * (NT * NT);
    float mreg[5];
#pragma unroll
    for (int ii = 0; ii < 5; ++ii) {
        int i = tid + ii * 512;
        mreg[ii] = (i < NT * NT) ? mb_[i] * LOG2E : 0.f;
    }

    // ---- stage V (lanes -> consecutive tokens; slot-permuted cols) ----
    for (int ii = 0; ii < 4; ++ii) {
        int i = ii * 64 + lane;
        int tt = 32 * half + (i & 31);
        int d0 = (i >> 5) * 4;
        short4 v4 = {0, 0, 0, 0};
        if (tt < NT) v4 = *reinterpret_cast<const short4*>(vg + tt * 32 + d0);
        int a = tt >> 4, bb2 = tt & 15;
        int col = (bb2 < 8) ? (a * 8 + bb2) : (24 + a * 8 + bb2);
        vSl[(d0 + 0) * 64 + (col ^ (((d0 + 0) & 7) << 3))] = v4.x;
        vSl[(d0 + 1) * 64 + (col ^ (((d0 + 1) & 7) << 3))] = v4.y;
        vSl[(d0 + 2) * 64 + (col ^ (((d0 + 2) & 7) << 3))] = v4.z;
        vSl[(d0 + 3) * 64 + (col ^ (((d0 + 3) & 7) << 3))] = v4.w;
    }
    __syncthreads();   // #1: mT zeroed (vS also staged)

    // ---- scatter mask regs -> mT transposed ----
#pragma unroll
    for (int ii = 0; ii < 5; ++ii) {
        int i = tid + ii * 512;
        if (i < NT * NT) {
            unsigned q_, k_;
            div49((unsigned)i, q_, k_);
            mT[k_ * 65 + q_] = mreg[ii];
        }
    }
    __syncthreads();   // #2: mT ready

    // ---- hoisted V fragments ----
    bf16x8 vb[2][2];
    const int sw8 = (lr & 7) << 3;
#pragma unroll
    for (int nt = 0; nt < 2; ++nt)
#pragma unroll
        for (int blk = 0; blk < 2; ++blk)
            vb[nt][blk] = *reinterpret_cast<const bf16x8*>(
                &vSl[(16 * nt + lr) * 64 + ((blk * 32 + 8 * lg) ^ sw8)]);

    // ---- hoisted mask+bias sums for BOTH mt iterations ----
    const unsigned short* biasTh = biasT + h * (NT * NT);
    float mbb[2][4][4];
#pragma unroll
    for (int mt2 = 0; mt2 < 2; ++mt2) {
        const int qcol = 16 * (mt0 + mt2) + lr;
#pragma unroll
        for (int ct = 0; ct < 4; ++ct)
#pragma unroll
            for (int r = 0; r < 4; ++r) {
                int k = 16 * ct + 4 * lg + r;
                int kc = min(k, 49);
                mbb[mt2][ct][r] = mT[kc * 65 + qcol] + bf2f(biasTh[kc * NT + qcol]);
            }
    }

    f32x4 oacc[2][2];
#pragma unroll
    for (int mt2 = 0; mt2 < 2; ++mt2) { oacc[mt2][0] = f32x4{0,0,0,0}; oacc[mt2][1] = f32x4{0,0,0,0}; }

#pragma unroll
    for (int mt2 = 0; mt2 < 2; ++mt2) {
        // swapped QK^T
        f32x4 sacc[4];
#pragma unroll
        for (int ct = 0; ct < 4; ++ct) {
            f32x4 z = {0.f, 0.f, 0.f, 0.f};
            sacc[ct] = __builtin_amdgcn_mfma_f32_16x16x32_bf16(kb[ct], qa[mt2], z, 0, 0, 0);
        }

        float e[4][4];
        float psum = 0.f;
#pragma unroll
        for (int ct = 0; ct < 4; ++ct)
#pragma unroll
            for (int r = 0; r < 4; ++r) {
                float ee = exp2f(sacc[ct][r] + mbb[mt2][ct][r]);
                if (ct == 3) ee = (r == 0 && lg == 0) ? ee : 0.f;
                e[ct][r] = ee;
                psum += ee;
            }
        psum += __shfl_xor(psum, 16);
        psum += __shfl_xor(psum, 32);
        const float inv = 1.0f / psum;

        unsigned A0 = pk2(e[0][0] * inv, e[0][1] * inv);
        unsigned A1 = pk2(e[1][0] * inv, e[1][1] * inv);
        unsigned A2 = pk2(e[2][0] * inv, e[2][1] * inv);
        unsigned A3 = pk2(e[3][0] * inv, e[3][1] * inv);
        unsigned B0 = pk2(e[0][2] * inv, e[0][3] * inv);
        unsigned B1 = pk2(e[1][2] * inv, e[1][3] * inv);
        unsigned B2 = pk2(e[2][2] * inv, e[2][3] * inv);
        unsigned B3 = pk2(e[3][2] * inv, e[3][3] * inv);
        pl32swap(A0, A2); pl32swap(A1, A3);
        pl16swap(A0, A1); pl16swap(A2, A3);
        pl32swap(B0, B2); pl32swap(B1, B3);
        pl16swap(B0, B1); pl16swap(B2, B3);
        union { unsigned u[4]; bf16x8 v; } p0, p1;
        p0.u[0] = A0; p0.u[1] = B0; p0.u[2] = A1; p0.u[3] = B1;
        p1.u[0] = A2; p1.u[1] = B2; p1.u[2] = A3; p1.u[3] = B3;

#pragma unroll
        for (int nt = 0; nt < 2; ++nt) {
            oacc[mt2][nt] = __builtin_amdgcn_mfma_f32_16x16x32_bf16(p0.v, vb[nt][0], oacc[mt2][nt], 0, 0, 0);
            oacc[mt2][nt] = __builtin_amdgcn_mfma_f32_16x16x32_bf16(p1.v, vb[nt][1], oacc[mt2][nt], 0, 0, 0);
        }
    }

    // ---- write o tile to LDS (no preceding barrier needed: dedicated buffer)
#pragma unroll
    for (int mt2 = 0; mt2 < 2; ++mt2)
#pragma unroll
        for (int nt = 0; nt < 2; ++nt)
#pragma unroll
            for (int r = 0; r < 4; ++r) {
                int row = 16 * (mt0 + mt2) + 4 * lg + r;
                int col = 32 * h + 16 * nt + lr;
                oS[swz128(row, col)] = f2bf(oacc[mt2][nt][r]);
            }
    __syncthreads();   // #3: o ready

    // ---- proj: wave w owns col-tile nt=w (16 cols), all 64 rows ----
    {
        f32x4 acc[4];
#pragma unroll
        for (int mf = 0; mf < 4; ++mf) acc[mf] = f32x4{0.f, 0.f, 0.f, 0.f};

#pragma unroll
        for (int mf = 0; mf < 4; ++mf) {
#pragma unroll
            for (int kt = 0; kt < 4; ++kt) {
                bf16x8 af = *reinterpret_cast<const bf16x8*>(&oS[swz128(16 * mf + lr, kt * 32 + lg * 8)]);
                acc[mf] = __builtin_amdgcn_mfma_f32_16x16x32_bf16(af, bbf[kt], acc[mf], 0, 0, 0);
            }
        }

        const int col = w * 16 + lr;
        const float pb = proj_b[col];
#pragma unroll
        for (int mf = 0; mf < 4; ++mf)
#pragma unroll
            for (int r = 0; r < 4; ++r) {
                int row = 16 * mf + 4 * lg + r;
                if (row < NT)
                    out[((size_t)b * NT + row) * CD + col] = acc[mf][r] + pb;
            }
    }
}

extern "C" void kernel_launch(void* const* d_in, const int* in_sizes, int n_in,
                              void* d_out, int out_size, void* d_ws, size_t ws_size,
                              hipStream_t stream) {
    const float* x      = (const float*)d_in[0];
    const float* mask   = (const float*)d_in[1];
    const float* qkv_w  = (const float*)d_in[2];
    const float* qkv_b  = (const float*)d_in[3];
    const float* rbt    = (const float*)d_in[4];
    const float* proj_w = (const float*)d_in[5];
    const float* proj_b = (const float*)d_in[6];
    const int*   ridx   = (const int*)d_in[7];
    float* out = (float*)d_out;

    char* ws = (char*)d_ws;
    short* qkvwS  = (short*)(ws + WS_QKVWT);
    short* projwT = (short*)(ws + WS_PROJWT);
    unsigned short* biasBf = (unsigned short*)(ws + WS_BIAS);
    short* qkv = (short*)(ws + WS_QKV);

    prep_kernel<<<192, 256, 0, stream>>>(qkv_w, proj_w, rbt, ridx, qkvwS, projwT, biasBf);
    qkv_gemm_kernel<<<(NB * NT) / 128, 256, 0, stream>>>(x, qkv_b, qkvwS, qkv);
    attn_proj_kernel<<<NB, 512, 0, stream>>>(qkv, mask, biasBf, projwT, proj_b, out);
}

// Round 12
// 296.739 us; speedup vs baseline: 1.3950x; 1.0540x over previous
//
#include <hip/hip_runtime.h>
#include <hip/hip_bf16.h>

using f32x4 = __attribute__((ext_vector_type(4))) float;
using bf16x8 = __attribute__((ext_vector_type(8))) short;

#define DEVI __device__ __forceinline__

DEVI short f2bf(float f) { __hip_bfloat16 h = __float2bfloat16(f); return *reinterpret_cast<short*>(&h); }
DEVI unsigned int pk2(float a, float b) {
    float2 t; t.x = a; t.y = b;
    __hip_bfloat162 h = __float22bfloat162_rn(t);
    return *reinterpret_cast<unsigned int*>(&h);
}
DEVI float bf2f(unsigned short s) { unsigned int u = ((unsigned int)s) << 16; return __uint_as_float(u); }

DEVI void pl32swap(unsigned& a, unsigned& b) { asm("v_permlane32_swap_b32 %0, %1" : "+v"(a), "+v"(b)); }
DEVI void pl16swap(unsigned& a, unsigned& b) { asm("v_permlane16_swap_b32 %0, %1" : "+v"(a), "+v"(b)); }

#define GLOAD_LDS16(gp, lp) \
    __builtin_amdgcn_global_load_lds((const __attribute__((address_space(1))) void*)(gp), \
                                     (__attribute__((address_space(3))) void*)(lp), 16, 0, 0)

constexpr int NB = 8192;
constexpr int NT = 49;
constexpr int CD = 128;
constexpr float SCALE = 0.17677669529663687f;
constexpr float LOG2E = 1.4426950408889634f;

// ---- ws layout (bytes) ----
constexpr size_t WS_QKVWT  = 0;        // 384*128 bf16 swizzled
constexpr size_t WS_PROJWT = 98304;    // 128*128 bf16 plain-transposed [n][k]
constexpr size_t WS_BIAS   = 131072;   // 4*2401 bf16 transposed [h][k][q] x LOG2E

DEVI void div49(unsigned grow, unsigned& bI, unsigned& tI) {
    bI = (unsigned)(((unsigned long long)grow * 2804876602ull) >> 37);
    tI = grow - bI * 49u;
}

DEVI int swz128(int row, int col) { return row * 128 + (col ^ ((row & 7) << 3)); }

// ============================================================================
// prep (unchanged from R11)
// ============================================================================
__global__ __launch_bounds__(256) void prep_kernel(
    const float* __restrict__ qkv_w, const float* __restrict__ proj_w,
    const float* __restrict__ rbt, const int* __restrict__ rel_index,
    short* __restrict__ qkvwS, short* __restrict__ projwT, unsigned short* __restrict__ biasBf)
{
    int i = blockIdx.x * 256 + threadIdx.x;
    if (i < 384 * 128) {
        int n = i >> 7, j = i & 127;
        int c = n >> 7, r = n & 127;
        qkvwS[c * 16384 + r * 128 + (j ^ ((r & 7) << 3))] = f2bf(qkv_w[j * 384 + n]);
    }
    if (i < 128 * 128) {
        int n = i >> 7, j = i & 127;
        projwT[n * 128 + j] = f2bf(proj_w[j * 128 + n]);
    }
    if (i < 4 * NT * NT) {
        int h = i / (NT * NT); int t = i % (NT * NT);
        int k = t / NT, q = t - k * NT;
        biasBf[i] = (unsigned short)f2bf(rbt[rel_index[q * NT + k] * 4 + h] * LOG2E);
    }
}

// ============================================================================
// FUSED kernel: block = 1 window (512 thr, 8 waves).
// LDS (80 KB exactly, 2 blocks/CU):
//   qkL  [4][64][64] shorts, granule-XOR (q granules 0-3, k 4-7)  32 KB  (later oS)
//   vS   [4][32d][64 slots] slot-permuted + XOR                   16 KB
//   Wc   weight chunk (32 KB, 3 chunks)                           32 KB  (later mT)
// P1: QKV GEMM -> LDS. P2: swapped-QK^T attn (R11 core). P3: proj -> out.
// ============================================================================
__global__ __launch_bounds__(512, 4) void fused_kernel(
    const float* __restrict__ x, const float* __restrict__ mask,
    const float* __restrict__ qkv_b, const short* __restrict__ qkvwS,
    const unsigned short* __restrict__ biasT, const short* __restrict__ projwT,
    const float* __restrict__ proj_b, float* __restrict__ out)
{
    __shared__ __attribute__((aligned(16))) short pool[40960];
    short* qkL = pool;                         // 16384 shorts
    short* vS  = pool + 16384;                 // 8192 shorts
    char*  Wcb = (char*)(pool + 24576);        // 32 KB
    float* mT  = (float*)(pool + 24576);       // aliases Wc (after P1)

    const int b = blockIdx.x;
    const int tid = threadIdx.x;
    const int w = tid >> 6, lane = tid & 63, lr = lane & 15, lg = lane >> 4;
    const int h = w >> 1, half = w & 1;

    // ---- mask prefetch to regs (independent, hides under P1) ----
    const float* mb_ = mask + (size_t)b * (NT * NT);
    float mreg[5];
#pragma unroll
    for (int ii = 0; ii < 5; ++ii) {
        int i = tid + ii * 512;
        mreg[ii] = (i < NT * NT) ? mb_[i] * LOG2E : 0.f;
    }

    // ---- A-fragments from x: wave covers rows 32*(w&1)..+32 (2 row-tiles) ----
    bf16x8 af[2][4];
#pragma unroll
    for (int mf = 0; mf < 2; ++mf) {
        const int row = 32 * (w & 1) + 16 * mf + lr;
        const bool valid = row < NT;
        const float* xrow = x + ((size_t)b * NT + (valid ? row : 0)) * CD;
#pragma unroll
        for (int kt = 0; kt < 4; ++kt) {
            float4 v0 = {0.f,0.f,0.f,0.f}, v1 = {0.f,0.f,0.f,0.f};
            if (valid) {
                const float4* p = reinterpret_cast<const float4*>(xrow + kt * 32 + lg * 8);
                v0 = p[0]; v1 = p[1];
            }
            union { unsigned int u[4]; bf16x8 v; } cv;
            cv.u[0] = pk2(v0.x, v0.y); cv.u[1] = pk2(v0.z, v0.w);
            cv.u[2] = pk2(v1.x, v1.y); cv.u[3] = pk2(v1.z, v1.w);
            af[mf][kt] = cv.v;
        }
    }

    // ---- qkv bias preload for this wave's 6 n-tiles ----
    float biasr[3][2];
#pragma unroll
    for (int c = 0; c < 3; ++c)
#pragma unroll
        for (int nn = 0; nn < 2; ++nn)
            biasr[c][nn] = qkv_b[(c * 8 + (w >> 1) + 4 * nn) * 16 + lr];

    // ================= P1: QKV GEMM (3 weight chunks) =================
    const char* srcW = (const char*)qkvwS;
#pragma unroll
    for (int c = 0; c < 3; ++c) {
#pragma unroll
        for (int i = 0; i < 4; ++i)
            GLOAD_LDS16(srcW + c * 32768 + w * 4096 + i * 1024 + lane * 16,
                        Wcb + w * 4096 + i * 1024);
        __syncthreads();

#pragma unroll
        for (int nn = 0; nn < 2; ++nn) {
            const int ntl = (w >> 1) + 4 * nn;       // chunk-local n-tile
            const int nt  = c * 8 + ntl;             // global n-tile
            const int s   = nt >> 3;                 // 0=q 1=k 2=v
            const int hh  = (nt >> 1) & 3;
            const int d0  = (nt & 1) * 16;
            const int d   = d0 + lr;
            const float scl = (s == 0) ? SCALE * LOG2E : 1.0f;
#pragma unroll
            for (int mf = 0; mf < 2; ++mf) {
                const int rt = 2 * (w & 1) + mf;
                f32x4 acc = {0.f, 0.f, 0.f, 0.f};
#pragma unroll
                for (int kt = 0; kt < 4; ++kt) {
                    bf16x8 bb = *reinterpret_cast<const bf16x8*>(
                        Wcb + (ntl * 16 + lr) * 256 + ((kt * 64 + lg * 16) ^ ((lr & 7) << 4)));
                    acc = __builtin_amdgcn_mfma_f32_16x16x32_bf16(af[mf][kt], bb, acc, 0, 0, 0);
                }
#pragma unroll
                for (int r = 0; r < 4; ++r) {
                    const int row = rt * 16 + 4 * lg + r;
                    const short val = f2bf((acc[r] + biasr[c][nn]) * scl);
                    if (s < 2) {
                        const int g0 = s * 4 + (d >> 3);
                        qkL[hh * 4096 + row * 64 + (((g0 ^ (row & 7)) << 3) | (d & 7))] = val;
                    } else {
                        const int a2 = row >> 4, bb2 = row & 15;
                        const int col = (bb2 < 8) ? (a2 * 8 + bb2) : (24 + a2 * 8 + bb2);
                        vS[hh * 2048 + d * 64 + (col ^ ((d & 7) << 3))] = val;
                    }
                }
            }
        }
        __syncthreads();
    }

    // ================= P2a: frag loads + mask scatter =================
    const int mt0 = 2 * half;
    bf16x8 qa[2], kb[4], vb[2][2];
#pragma unroll
    for (int i = 0; i < 2; ++i) {
        const int row = 16 * (mt0 + i) + lr;
        qa[i] = *reinterpret_cast<const bf16x8*>(&qkL[h * 4096 + row * 64 + ((lg ^ (row & 7)) << 3)]);
    }
#pragma unroll
    for (int t4 = 0; t4 < 4; ++t4) {
        const int row = 16 * t4 + lr;
        kb[t4] = *reinterpret_cast<const bf16x8*>(&qkL[h * 4096 + row * 64 + (((4 | lg) ^ (row & 7)) << 3)]);
    }
    {
        const short* vSl = vS + h * 2048;
        const int sw8 = (lr & 7) << 3;
#pragma unroll
        for (int nt = 0; nt < 2; ++nt)
#pragma unroll
            for (int blk = 0; blk < 2; ++blk)
                vb[nt][blk] = *reinterpret_cast<const bf16x8*>(
                    &vSl[(16 * nt + lr) * 64 + ((blk * 32 + 8 * lg) ^ sw8)]);
    }
    // scatter mask regs -> mT transposed (Wc region is dead)
#pragma unroll
    for (int ii = 0; ii < 5; ++ii) {
        int i = tid + ii * 512;
        if (i < NT * NT) {
            unsigned q_, k_;
            div49((unsigned)i, q_, k_);
            mT[k_ * 65 + q_] = mreg[ii];
        }
    }
    __syncthreads();

    // ================= P2b: attn (R11 core) =================
    const unsigned short* biasTh = biasT + h * (NT * NT);
    float mbb[2][4][4];
#pragma unroll
    for (int mt2 = 0; mt2 < 2; ++mt2) {
        const int qcol = 16 * (mt0 + mt2) + lr;
#pragma unroll
        for (int ct = 0; ct < 4; ++ct)
#pragma unroll
            for (int r = 0; r < 4; ++r) {
                int k = 16 * ct + 4 * lg + r;
                int kc = min(k, 49);
                mbb[mt2][ct][r] = mT[kc * 65 + qcol] + bf2f(biasTh[kc * NT + qcol]);
            }
    }

    f32x4 oacc[2][2];
#pragma unroll
    for (int mt2 = 0; mt2 < 2; ++mt2) { oacc[mt2][0] = f32x4{0,0,0,0}; oacc[mt2][1] = f32x4{0,0,0,0}; }

#pragma unroll
    for (int mt2 = 0; mt2 < 2; ++mt2) {
        f32x4 sacc[4];
#pragma unroll
        for (int ct = 0; ct < 4; ++ct) {
            f32x4 z = {0.f, 0.f, 0.f, 0.f};
            sacc[ct] = __builtin_amdgcn_mfma_f32_16x16x32_bf16(kb[ct], qa[mt2], z, 0, 0, 0);
        }

        float e[4][4];
        float psum = 0.f;
#pragma unroll
        for (int ct = 0; ct < 4; ++ct)
#pragma unroll
            for (int r = 0; r < 4; ++r) {
                float ee = exp2f(sacc[ct][r] + mbb[mt2][ct][r]);
                if (ct == 3) ee = (r == 0 && lg == 0) ? ee : 0.f;
                e[ct][r] = ee;
                psum += ee;
            }
        psum += __shfl_xor(psum, 16);
        psum += __shfl_xor(psum, 32);
        const float inv = 1.0f / psum;

        unsigned A0 = pk2(e[0][0] * inv, e[0][1] * inv);
        unsigned A1 = pk2(e[1][0] * inv, e[1][1] * inv);
        unsigned A2 = pk2(e[2][0] * inv, e[2][1] * inv);
        unsigned A3 = pk2(e[3][0] * inv, e[3][1] * inv);
        unsigned B0 = pk2(e[0][2] * inv, e[0][3] * inv);
        unsigned B1 = pk2(e[1][2] * inv, e[1][3] * inv);
        unsigned B2 = pk2(e[2][2] * inv, e[2][3] * inv);
        unsigned B3 = pk2(e[3][2] * inv, e[3][3] * inv);
        pl32swap(A0, A2); pl32swap(A1, A3);
        pl16swap(A0, A1); pl16swap(A2, A3);
        pl32swap(B0, B2); pl32swap(B1, B3);
        pl16swap(B0, B1); pl16swap(B2, B3);
        union { unsigned u[4]; bf16x8 v; } p0, p1;
        p0.u[0] = A0; p0.u[1] = B0; p0.u[2] = A1; p0.u[3] = B1;
        p1.u[0] = A2; p1.u[1] = B2; p1.u[2] = A3; p1.u[3] = B3;

#pragma unroll
        for (int nt = 0; nt < 2; ++nt) {
            oacc[mt2][nt] = __builtin_amdgcn_mfma_f32_16x16x32_bf16(p0.v, vb[nt][0], oacc[mt2][nt], 0, 0, 0);
            oacc[mt2][nt] = __builtin_amdgcn_mfma_f32_16x16x32_bf16(p1.v, vb[nt][1], oacc[mt2][nt], 0, 0, 0);
        }
    }

    // ---- write o tile into qkL region (dead after P2a frag loads) ----
    short* oS = qkL;
#pragma unroll
    for (int mt2 = 0; mt2 < 2; ++mt2)
#pragma unroll
        for (int nt = 0; nt < 2; ++nt)
#pragma unroll
            for (int r = 0; r < 4; ++r) {
                int row = 16 * (mt0 + mt2) + 4 * lg + r;
                int col = 32 * h + 16 * nt + lr;
                oS[swz128(row, col)] = f2bf(oacc[mt2][nt][r]);
            }
    __syncthreads();

    // ================= P3: proj (wave w -> col-tile w) =================
    {
        bf16x8 bbf[4];
        const short* brow = projwT + (w * 16 + lr) * 128 + lg * 8;
#pragma unroll
        for (int kt = 0; kt < 4; ++kt)
            bbf[kt] = *reinterpret_cast<const bf16x8*>(brow + kt * 32);

        f32x4 acc[4];
#pragma unroll
        for (int mf = 0; mf < 4; ++mf) acc[mf] = f32x4{0.f, 0.f, 0.f, 0.f};

#pragma unroll
        for (int mf = 0; mf < 4; ++mf)
#pragma unroll
            for (int kt = 0; kt < 4; ++kt) {
                bf16x8 a2 = *reinterpret_cast<const bf16x8*>(&oS[swz128(16 * mf + lr, kt * 32 + lg * 8)]);
                acc[mf] = __builtin_amdgcn_mfma_f32_16x16x32_bf16(a2, bbf[kt], acc[mf], 0, 0, 0);
            }

        const int col = w * 16 + lr;
        const float pb = proj_b[col];
#pragma unroll
        for (int mf = 0; mf < 4; ++mf)
#pragma unroll
            for (int r = 0; r < 4; ++r) {
                int row = 16 * mf + 4 * lg + r;
                if (row < NT)
                    out[((size_t)b * NT + row) * CD + col] = acc[mf][r] + pb;
            }
    }
}

extern "C" void kernel_launch(void* const* d_in, const int* in_sizes, int n_in,
                              void* d_out, int out_size, void* d_ws, size_t ws_size,
                              hipStream_t stream) {
    const float* x      = (const float*)d_in[0];
    const float* mask   = (const float*)d_in[1];
    const float* qkv_w  = (const float*)d_in[2];
    const float* qkv_b  = (const float*)d_in[3];
    const float* rbt    = (const float*)d_in[4];
    const float* proj_w = (const float*)d_in[5];
    const float* proj_b = (const float*)d_in[6];
    const int*   ridx   = (const int*)d_in[7];
    float* out = (float*)d_out;

    char* ws = (char*)d_ws;
    short* qkvwS  = (short*)(ws + WS_QKVWT);
    short* projwT = (short*)(ws + WS_PROJWT);
    unsigned short* biasBf = (unsigned short*)(ws + WS_BIAS);

    prep_kernel<<<192, 256, 0, stream>>>(qkv_w, proj_w, rbt, ridx, qkvwS, projwT, biasBf);
    fused_kernel<<<NB, 512, 0, stream>>>(x, mask, qkv_b, qkvwS, biasBf, projwT, proj_b, out);
}